// Round 9
// baseline (1002.312 us; speedup 1.0000x reference)
//
#include <hip/hip_runtime.h>
#include <cstdint>
#include <cstddef>
#include <type_traits>

// ---------------- problem constants ----------------
#define OUT_DIM    65
#define TREE_STRIDE 66
#define N_NODE     1023
#define N_INTN     511

typedef _Float16 f16;
typedef _Float16 f16x8 __attribute__((ext_vector_type(8)));
typedef _Float16 f16x4 __attribute__((ext_vector_type(4)));
typedef float    f32x4 __attribute__((ext_vector_type(4)));

template<int V> using ic = std::integral_constant<int, V>;

#define MFMA(a, b, c) __builtin_amdgcn_mfma_f32_16x16x32_f16((a), (b), (c), 0, 0, 0)

// counted wait, compile-time immediates; "memory" clobber pins load scheduling.
// Correctness never relies on these (compiler emits its own waits before each
// use of a loaded value); they only ADD earlier/looser waits for scheduling.
template<int VM, int LG>
__device__ __forceinline__ void waitcnt_t() {
  asm volatile("s_waitcnt vmcnt(%0) lgkmcnt(%1)" :: "n"(VM), "n"(LG) : "memory");
}

// H swizzle: elem(row,k) at row*512 + (((k>>3) ^ (row&15))<<3) + (k&7)
template<int MT>
__device__ __forceinline__ void storeH_fn(f16* __restrict__ H, f32x4 (&acc)[MT][4],
                                          const float* __restrict__ bias,
                                          int wcb, int quad, int l16) {
#pragma unroll
  for (int mt = 0; mt < MT; mt++) {
#pragma unroll
    for (int nt = 0; nt < 4; nt++) {
      const int c0 = wcb + nt * 16 + quad * 4;
      const float4 bv = *(const float4*)(bias + c0);
      f16x4 hv;
      float v0 = acc[mt][nt][0] + bv.x; hv[0] = (f16)(v0 > 0.f ? v0 : 0.f);
      float v1 = acc[mt][nt][1] + bv.y; hv[1] = (f16)(v1 > 0.f ? v1 : 0.f);
      float v2 = acc[mt][nt][2] + bv.z; hv[2] = (f16)(v2 > 0.f ? v2 : 0.f);
      float v3 = acc[mt][nt][3] + bv.w; hv[3] = (f16)(v3 > 0.f ? v3 : 0.f);
      const int row = mt * 16 + l16;
      *(f16x4*)&H[row * 512 + (((c0 >> 3) ^ l16) << 3) + (quad & 1) * 4] = hv;
    }
  }
}

// ---------------------------------------------------------------------------
// Barrier-free K-loop. B: global->VGPR from FRAGMENT-LINEAR weights (one
// coalesced 1KB dwordx4 per load). A: ds_read from stable LDS. Rings: BD=2
// for B (prefetch distance 1 chunk ~700cy covers L2 latency), AD=1 for A
// (LDS latency hides under the co-resident wave's MFMA region). Counted
// waits only; no __syncthreads inside.
// Register budget (the binding constraint, rounds 4-8): occupancy steps at
// total(arch+acc) 64/128/256 on the unified gfx950 file. MT=8 => acc=128
// AGPR + bs 32 + as 32 + addr ~30 = ~225 <= 256 cap of (512,2). Anything
// past 256 spills catastrophically (rounds 4/5/7: 330MB-3GB scratch).
// ---------------------------------------------------------------------------
template<int NC, int MT, int NT, int BD, int AD, bool SWAP,
         typename GetB, typename GetA>
__device__ __forceinline__ void kloop(GetB getB, GetA getA, f32x4 (&acc)[MT][NT])
{
  f16x8 bs[BD][NT];
  f16x8 as[AD][MT];
#pragma unroll
  for (int c = 0; c < BD - 1 && c < NC; c++)
#pragma unroll
    for (int nt = 0; nt < NT; nt++) bs[c][nt] = getB(c, nt);
#pragma unroll
  for (int c = 0; c < AD - 1 && c < NC; c++)
#pragma unroll
    for (int mt = 0; mt < MT; mt++) as[c][mt] = getA(c, mt);

  auto lp = [&](auto&& self, auto Cc) -> void {
    constexpr int C = decltype(Cc)::value;
    if constexpr (C < NC) {
      if constexpr (C + BD - 1 < NC) {
#pragma unroll
        for (int nt = 0; nt < NT; nt++) bs[(C + BD - 1) % BD][nt] = getB(C + BD - 1, nt);
      }
      if constexpr (C + AD - 1 < NC) {
#pragma unroll
        for (int mt = 0; mt < MT; mt++) as[(C + AD - 1) % AD][mt] = getA(C + AD - 1, mt);
      }
      constexpr int BOUT = (BD - 1) < (NC - 1 - C) ? (BD - 1) : (NC - 1 - C);
      constexpr int AOUT = (AD - 1) < (NC - 1 - C) ? (AD - 1) : (NC - 1 - C);
      waitcnt_t<NT * BOUT, MT * AOUT>();
      __builtin_amdgcn_s_setprio(1);
#pragma unroll
      for (int mt = 0; mt < MT; mt++)
#pragma unroll
        for (int nt = 0; nt < NT; nt++)
          acc[mt][nt] = SWAP ? MFMA(bs[C % BD][nt], as[C % AD][mt], acc[mt][nt])
                             : MFMA(as[C % AD][mt], bs[C % BD][nt], acc[mt][nt]);
      __builtin_amdgcn_s_setprio(0);
      self(self, ic<C + 1>{});
    }
  };
  lp(lp, ic<0>{});
}

// one 512-col layer, 128 rows (MT=8), 8 waves each owning 64 cols.
// B fragment-linear: frag(c, cb, lane) at ((c*32 + cb)*64 + lane)*8 f16,
// cb = wave*4 + nt.
template<int K, typename GetA>
__device__ __forceinline__ void run_layer(
    const f16* __restrict__ Wt, const float* __restrict__ bias,
    f16* __restrict__ H, int wave, int lane, int quad, int l16, GetA getA)
{
  constexpr int NC = K / 32;
  const int wcb = wave * 64;
  const f16* bbase = Wt + (long)(wave * 4) * 512 + lane * 8;
  auto getB = [&](int c, int nt) -> f16x8 {
    return *(const f16x8*)(bbase + (long)(c * 32 + nt) * 512);
  };
  f32x4 acc[8][4];
#pragma unroll
  for (int i = 0; i < 8; i++)
#pragma unroll
    for (int j = 0; j < 4; j++) acc[i][j] = f32x4{0.f, 0.f, 0.f, 0.f};

  kloop<NC, 8, 4, 2, 1, true>(getB, getA, acc);   // swapped: row=l16, col=quad*4+r

  __syncthreads();                 // all H/X reads of this layer done
  storeH_fn<8>(H, acc, bias, wcb, quad, l16);
  __syncthreads();                 // H visible for next layer
}

// ---------------- fused 4-layer MLP, 128 rows/block, 512 thr, any level -----
// LDS: H[128][512] f16 = 128KB. X (layer-0 input) aliases H — safe: storeH(l0)
// writes H only after the barrier when all X reads are done.
//   leaf X[128][72]  (stride 72 f16: rows 0-7 cover all 32 banks, 2-way free)
//   int  X[128][232] (stride 232 f16: same property)
// Occupancy: 8 waves/CU (1 block) — set by the 256-reg bucket, NOT LDS, so
// the 128KB LDS costs nothing extra (rounds 6/8 measured 21% = same).
__global__ __launch_bounds__(512, 2) void fused_mlp(
    const float* __restrict__ feats,
    const f16* __restrict__ w0t, const float* __restrict__ b0,
    const f16* __restrict__ w1t, const float* __restrict__ b1,
    const f16* __restrict__ w2t, const float* __restrict__ b2,
    const f16* __restrict__ wot, const float* __restrict__ bo,
    f16* __restrict__ tree, float* __restrict__ dOut, int lvl, int leaf)
{
  extern __shared__ f16 S[];
  f16* H = S;            // 65536 f16 = 128KB
  f16* X = S;            // layer-0 input (alias of H)

  const int tid  = threadIdx.x;
  const int wave = tid >> 6;
  const int lane = tid & 63;
  const int quad = lane >> 4;
  const int l16  = lane & 15;
  const long rowBase = (long)blockIdx.x * 128;

  if (leaf) {
    // stage feats f32->f16 into X[128][72] (coalesced rows)
    for (int i = tid; i < 8192; i += 512) {
      int r = i >> 6, cc = i & 63;
      X[r * 72 + cc] = (f16)feats[(rowBase + r) * 64 + cc];
    }
    __syncthreads();
  } else {
    // feats: 128 rows x 64, f32->f16, coalesced; per-row (batch,node) map
    for (int i = tid; i < 8192; i += 512) {
      int r = i >> 6, cc = i & 63;
      long rg = rowBase + r;
      long bbr = rg >> lvl;
      long ii = rg - (bbr << lvl);
      long nn = (1L << lvl) - 1 + ii;
      X[r * 232 + cc] = (f16)feats[(bbr * N_INTN + nn) * 64 + cc];
    }
    // children: 128 rows x 132 f16 VERBATIM copy (66 u32/row, contiguous).
    // Junk cols (col65 of each child) land at k=129,195: weight rows there
    // are ZERO (hole repack + K bound), and tree col65 is zeroed by every
    // epilogue, so junk is finite -> 0*finite = 0.
    for (int i = tid; i < 8448; i += 512) {
      int r = i / 66, c = i - r * 66;
      long rg = rowBase + r;
      long bbr = rg >> lvl;
      long ii = rg - (bbr << lvl);
      long nn = (1L << lvl) - 1 + ii;
      const uint32_t* src = (const uint32_t*)(tree + (bbr * N_NODE + 2 * nn + 1) * TREE_STRIDE);
      *(uint32_t*)(X + r * 232 + 64 + 2 * c) = src[c];
    }
    // zero k=196..223 (read range ends at 223; avoid NaN*0)
    for (int i = tid; i < 3584; i += 512) {
      int r = i / 28, cc = i - r * 28;
      X[r * 232 + 196 + cc] = (f16)0.f;
    }
    __syncthreads();
  }

  // ---- layer 0 (A from X) ----
  if (leaf) {
    auto gA = [&](int c, int mt) -> f16x8 {
      int row = mt * 16 + l16;
      return *(const f16x8*)&X[row * 72 + c * 32 + quad * 8];   // max 63 < 72
    };
    run_layer<64>(w0t, b0, H, wave, lane, quad, l16, gA);
  } else {
    auto gA = [&](int c, int mt) -> f16x8 {
      int row = mt * 16 + l16;
      return *(const f16x8*)&X[row * 232 + c * 32 + quad * 8];  // max 223 < 232
    };
    run_layer<224>(w0t, b0, H, wave, lane, quad, l16, gA);
  }

  // ---- mid layers (A from H) ----
  auto getAH = [&](int c, int mt) -> f16x8 {
    int row = mt * 16 + l16;
    return *(const f16x8*)&H[row * 512 + ((((c * 4 + quad) ^ l16) << 3))];
  };
  run_layer<512>(w1t, b1, H, wave, lane, quad, l16, getAH);
  run_layer<512>(w2t, b2, H, wave, lane, quad, l16, getAH);

  // ---- out layer (512 -> 65), all 8 waves, 16 rows each ----
  {
    const f16* obase = wot + lane * 8;             // frag-linear, NB=5
    auto gB = [&](int c, int nt) -> f16x8 {
      return *(const f16x8*)(obase + (long)(c * 5 + nt) * 512);
    };
    const int orow = wave * 16 + l16;
    auto gA = [&](int c, int mt) -> f16x8 {
      return *(const f16x8*)&H[orow * 512 + ((((c * 4 + quad) ^ l16) << 3))];
    };
    f32x4 oacc[1][5];
#pragma unroll
    for (int i = 0; i < 5; i++) oacc[0][i] = f32x4{0.f, 0.f, 0.f, 0.f};

    kloop<16, 1, 5, 2, 1, false>(gB, gA, oacc);    // normal: row=quad*4+r, col=nt*16+l16

#pragma unroll
    for (int nt = 0; nt < 5; nt++)
#pragma unroll
      for (int r = 0; r < 4; r++) {
        int col = nt * 16 + l16;
        long rg = rowBase + wave * 16 + quad * 4 + r;
        long b2_ = rg >> lvl;
        long ii  = rg - (b2_ << lvl);
        long node = (1L << lvl) - 1 + ii;
        if (col < OUT_DIM) {
          float v = oacc[0][nt][r] + bo[col];
          tree[(b2_ * N_NODE + node) * TREE_STRIDE + col] = (f16)v;
          if (lvl == 0 && col == 0) dOut[rg] = v;   // lvl 0: rg = batch index
        } else if (col == OUT_DIM) {
          // zero the pad col so child verbatim-copies read finite junk
          tree[(b2_ * N_NODE + node) * TREE_STRIDE + col] = (f16)0.f;
        }
      }
  }
}

// ---------------- weight repack: transpose+cast to FRAGMENT-LINEAR ----------
// elem e of a segment: j=e&7, lane=(e>>3)&63, q=e>>9, cb=q%NB, c=q/NB;
// stores W[k= c*32+(lane>>4)*8+j][col= cb*16+(lane&15)] (0-padded).
// hole: logical row `hole` is a ZERO row and source rows shift by 1 above it
// (maps the verbatim child-copy junk slots k=129/195 to zero weights).
struct WSeg { const float* W; f16* Wt; int K, N, NB, hole, start; };
struct WPack { WSeg s[8]; int total; };

__global__ void wcast_all(WPack p) {
  int idx = blockIdx.x * 256 + threadIdx.x;
  if (idx >= p.total) return;
  int si = 0;
#pragma unroll
  for (int i = 1; i < 8; i++) if (idx >= p.s[i].start) si = i;
  WSeg sg = p.s[si];
  int e = idx - sg.start;
  int j = e & 7, lane = (e >> 3) & 63, q = e >> 9;
  int cb = q % sg.NB, c = q / sg.NB;
  int col = cb * 16 + (lane & 15);
  int k = c * 32 + (lane >> 4) * 8 + j;
  int srck = (k < sg.hole) ? k : k - 1;
  float v = (k != sg.hole && srck < sg.K && col < sg.N)
                ? sg.W[(long)srck * sg.N + col] : 0.f;
  sg.Wt[e] = (f16)v;
}

// ---------------- host orchestration ----------------
extern "C" void kernel_launch(void* const* d_in, const int* in_sizes, int n_in,
                              void* d_out, int out_size, void* d_ws, size_t ws_size,
                              hipStream_t stream) {
  const float* leaf_feats     = (const float*)d_in[0];
  const float* internal_feats = (const float*)d_in[1];
  const float* lw0 = (const float*)d_in[2];
  const float* lb0 = (const float*)d_in[3];
  const float* lw1 = (const float*)d_in[4];
  const float* lb1 = (const float*)d_in[5];
  const float* lw2 = (const float*)d_in[6];
  const float* lb2 = (const float*)d_in[7];
  const float* lwo = (const float*)d_in[8];
  const float* lbo = (const float*)d_in[9];
  const float* iw0 = (const float*)d_in[10];
  const float* ib0 = (const float*)d_in[11];
  const float* iw1 = (const float*)d_in[12];
  const float* ib1 = (const float*)d_in[13];
  const float* iw2 = (const float*)d_in[14];
  const float* ib2 = (const float*)d_in[15];
  const float* iwo = (const float*)d_in[16];
  const float* ibo = (const float*)d_in[17];
  float* dOut = (float*)d_out;

  char* ws = (char*)d_ws;
  size_t off = 0;
  auto alloc = [&](size_t bytes) -> void* {
    void* p = ws + off;
    off += (bytes + 255) & ~(size_t)255;
    return p;
  };

  f16* lw0t = (f16*)alloc((size_t)64  * 512 * 2);
  f16* lw1t = (f16*)alloc((size_t)512 * 512 * 2);
  f16* lw2t = (f16*)alloc((size_t)512 * 512 * 2);
  f16* lwot = (f16*)alloc((size_t)512 * 80  * 2);
  f16* iw0t = (f16*)alloc((size_t)224 * 512 * 2);
  f16* iw1t = (f16*)alloc((size_t)512 * 512 * 2);
  f16* iw2t = (f16*)alloc((size_t)512 * 512 * 2);
  f16* iwot = (f16*)alloc((size_t)512 * 80  * 2);
  f16* tree = (f16*)alloc((size_t)256 * N_NODE * TREE_STRIDE * 2);

  const int NOHOLE = 1 << 30;
  WPack p;
  int cum = 0;
  auto seg = [&](int i, const float* W, f16* Wt, int K, int N, int Kpad, int NB, int hole) {
    p.s[i] = {W, Wt, K, N, NB, hole, cum};
    cum += Kpad * NB * 16;
  };
  seg(0, lw0, lw0t, 64, 512, 64, 32, NOHOLE);
  seg(1, lw1, lw1t, 512, 512, 512, 32, NOHOLE);
  seg(2, lw2, lw2t, 512, 512, 512, 32, NOHOLE);
  seg(3, lwo, lwot, 512, 65, 512, 5, NOHOLE);
  seg(4, iw0, iw0t, 194, 512, 224, 32, 129);   // hole at k=129 (left child pad)
  seg(5, iw1, iw1t, 512, 512, 512, 32, NOHOLE);
  seg(6, iw2, iw2t, 512, 512, 512, 32, NOHOLE);
  seg(7, iwo, iwot, 512, 65, 512, 5, NOHOLE);
  p.total = cum;
  wcast_all<<<dim3((cum + 255) / 256), dim3(256), 0, stream>>>(p);

  static bool attrSet = false;
  if (!attrSet) {
    hipFuncSetAttribute(reinterpret_cast<const void*>(fused_mlp),
                        hipFuncAttributeMaxDynamicSharedMemorySize, 131072);
    attrSet = true;
  }

  const size_t shmem = 131072;   // H 128KB (X aliased)

  // leaf pass: 131072 rows -> nodes 511..1022
  fused_mlp<<<dim3(1024), dim3(512), shmem, stream>>>(
      leaf_feats, lw0t, lb0, lw1t, lb1, lw2t, lb2, lwot, lbo, tree, dOut, 9, 1);

  // internal levels 8..0 (grid = rows/128 = 2<<l; weights stay L2-hot)
  for (int l = 8; l >= 0; l--) {
    fused_mlp<<<dim3(2u << l), dim3(512), shmem, stream>>>(
        internal_feats, iw0t, ib0, iw1t, ib1, iw2t, ib2, iwot, ibo, tree, dOut, l, 0);
  }

  (void)in_sizes; (void)n_in; (void)out_size; (void)ws_size;
}

// Round 10
// 840.172 us; speedup vs baseline: 1.1930x; 1.1930x over previous
//
#include <hip/hip_runtime.h>
#include <cstdint>
#include <cstddef>
#include <type_traits>

// ---------------- problem constants ----------------
#define OUT_DIM    65
#define TREE_STRIDE 66
#define N_NODE     1023
#define N_INTN     511

typedef _Float16 f16;
typedef _Float16 f16x8 __attribute__((ext_vector_type(8)));
typedef _Float16 f16x4 __attribute__((ext_vector_type(4)));
typedef float    f32x4 __attribute__((ext_vector_type(4)));

template<int V> using ic = std::integral_constant<int, V>;

#define MFMA(a, b, c) __builtin_amdgcn_mfma_f32_16x16x32_f16((a), (b), (c), 0, 0, 0)

// counted wait, compile-time immediates; "memory" clobber pins load scheduling.
// Correctness never relies on these (compiler emits its own waits before each
// use of a loaded value); they only ADD earlier/looser waits for scheduling.
template<int VM, int LG>
__device__ __forceinline__ void waitcnt_t() {
  asm volatile("s_waitcnt vmcnt(%0) lgkmcnt(%1)" :: "n"(VM), "n"(LG) : "memory");
}

// H swizzle: elem(row,k) at row*512 + (((k>>3) ^ (row&15))<<3) + (k&7)
template<int MT>
__device__ __forceinline__ void storeH_fn(f16* __restrict__ H, f32x4 (&acc)[MT][4],
                                          const float* __restrict__ bias,
                                          int wcb, int quad, int l16) {
#pragma unroll
  for (int mt = 0; mt < MT; mt++) {
#pragma unroll
    for (int nt = 0; nt < 4; nt++) {
      const int c0 = wcb + nt * 16 + quad * 4;
      const float4 bv = *(const float4*)(bias + c0);
      f16x4 hv;
      float v0 = acc[mt][nt][0] + bv.x; hv[0] = (f16)(v0 > 0.f ? v0 : 0.f);
      float v1 = acc[mt][nt][1] + bv.y; hv[1] = (f16)(v1 > 0.f ? v1 : 0.f);
      float v2 = acc[mt][nt][2] + bv.z; hv[2] = (f16)(v2 > 0.f ? v2 : 0.f);
      float v3 = acc[mt][nt][3] + bv.w; hv[3] = (f16)(v3 > 0.f ? v3 : 0.f);
      const int row = mt * 16 + l16;
      *(f16x4*)&H[row * 512 + (((c0 >> 3) ^ l16) << 3) + (quad & 1) * 4] = hv;
    }
  }
}

// ---------------------------------------------------------------------------
// MT=8 K-loop with QUARTER-chunk A streaming (the register diet that makes
// 128 rows/block fit): bs[2][4]=32 + as[2][2]=16 ring regs (round 9's
// as[1][8]=32 overflowed the 128-arch half of the unified file -> spill).
// Per chunk C: issue B(C+1) (4 coalesced 1KB loads), then 4 quarters of
// {issue next-quarter's 2 ds_reads -> counted wait -> 2mt x 4nt MFMA}.
// Per-wave lgkm stalls (~80cy/quarter) are covered by the co-resident wave.
// No __syncthreads inside — waves drift freely.
// ---------------------------------------------------------------------------
template<int NC, bool SWAP, typename GetB, typename GetA>
__device__ __forceinline__ void kloopQ(GetB getB, GetA getA, f32x4 (&acc)[8][4])
{
  f16x8 bs[2][4];
  f16x8 as[2][2];
#pragma unroll
  for (int nt = 0; nt < 4; nt++) bs[0][nt] = getB(0, nt);
#pragma unroll
  for (int m = 0; m < 2; m++) as[0][m] = getA(0, m);

  auto lp = [&](auto&& self, auto Cc) -> void {
    constexpr int C = decltype(Cc)::value;
    if constexpr (C < NC) {
      constexpr bool moreB = (C + 1 < NC);
      if constexpr (moreB) {
#pragma unroll
        for (int nt = 0; nt < 4; nt++) bs[(C + 1) & 1][nt] = getB(C + 1, nt);
      }
      auto qs = [&](auto&& qself, auto Qc) -> void {
        constexpr int Q = decltype(Qc)::value;
        if constexpr (Q < 4) {
          constexpr bool nextA = (Q < 3) || moreB;
          if constexpr (nextA) {
            constexpr int nc2 = (Q < 3) ? C : C + 1;
            constexpr int nm  = (Q < 3) ? (Q + 1) * 2 : 0;
#pragma unroll
            for (int m = 0; m < 2; m++) as[(Q + 1) & 1][m] = getA(nc2, nm + m);
          }
          if constexpr (Q == 0) waitcnt_t<moreB ? 4 : 0, nextA ? 2 : 0>();
          else                  waitcnt_t<63, nextA ? 2 : 0>();  // lgkm-only
          __builtin_amdgcn_s_setprio(1);
#pragma unroll
          for (int mq = 0; mq < 2; mq++)
#pragma unroll
            for (int nt = 0; nt < 4; nt++)
              acc[Q * 2 + mq][nt] =
                  SWAP ? MFMA(bs[C & 1][nt], as[Q & 1][mq], acc[Q * 2 + mq][nt])
                       : MFMA(as[Q & 1][mq], bs[C & 1][nt], acc[Q * 2 + mq][nt]);
          __builtin_amdgcn_s_setprio(0);
          qself(qself, ic<Q + 1>{});
        }
      };
      qs(qs, ic<0>{});
      self(self, ic<C + 1>{});
    }
  };
  lp(lp, ic<0>{});
}

// generic small kloop (out layer only): B ring BD=2, A issued+waited per chunk
template<int NC, int MT, int NT, bool SWAP, typename GetB, typename GetA>
__device__ __forceinline__ void kloop(GetB getB, GetA getA, f32x4 (&acc)[MT][NT])
{
  f16x8 bs[2][NT];
  f16x8 as[MT];
#pragma unroll
  for (int nt = 0; nt < NT; nt++) bs[0][nt] = getB(0, nt);

  auto lp = [&](auto&& self, auto Cc) -> void {
    constexpr int C = decltype(Cc)::value;
    if constexpr (C < NC) {
      if constexpr (C + 1 < NC) {
#pragma unroll
        for (int nt = 0; nt < NT; nt++) bs[(C + 1) & 1][nt] = getB(C + 1, nt);
      }
#pragma unroll
      for (int mt = 0; mt < MT; mt++) as[mt] = getA(C, mt);
      waitcnt_t<(C + 1 < NC) ? NT : 0, 0>();
      __builtin_amdgcn_s_setprio(1);
#pragma unroll
      for (int mt = 0; mt < MT; mt++)
#pragma unroll
        for (int nt = 0; nt < NT; nt++)
          acc[mt][nt] = SWAP ? MFMA(bs[C & 1][nt], as[mt], acc[mt][nt])
                             : MFMA(as[mt], bs[C & 1][nt], acc[mt][nt]);
      __builtin_amdgcn_s_setprio(0);
      self(self, ic<C + 1>{});
    }
  };
  lp(lp, ic<0>{});
}

// one 512-col layer, 128 rows (MT=8), 8 waves each owning 64 cols.
// B fragment-linear: frag(c, cb, lane) at ((c*32 + cb)*64 + lane)*8 f16.
template<int K, typename GetA>
__device__ __forceinline__ void run_layer(
    const f16* __restrict__ Wt, const float* __restrict__ bias,
    f16* __restrict__ H, int wave, int lane, int quad, int l16, GetA getA)
{
  constexpr int NC = K / 32;
  const int wcb = wave * 64;
  const f16* bbase = Wt + (long)(wave * 4) * 512 + lane * 8;
  auto getB = [&](int c, int nt) -> f16x8 {
    return *(const f16x8*)(bbase + (long)(c * 32 + nt) * 512);
  };
  f32x4 acc[8][4];
#pragma unroll
  for (int i = 0; i < 8; i++)
#pragma unroll
    for (int j = 0; j < 4; j++) acc[i][j] = f32x4{0.f, 0.f, 0.f, 0.f};

  kloopQ<NC, true>(getB, getA, acc);   // swapped: row=l16, col=quad*4+r

  __syncthreads();                 // all H/X reads of this layer done
  storeH_fn<8>(H, acc, bias, wcb, quad, l16);
  __syncthreads();                 // H visible for next layer
}

// ---------------- fused 4-layer MLP, 128 rows/block, 512 thr, any level -----
// LDS: H[128][512] f16 = 128KB. X (layer-0 input) aliases H — safe: storeH(l0)
// writes H only after the barrier when all X reads are done.
//   leaf X[128][72], internal X[128][232] (strides spread banks, 2-way free).
// Occupancy: 8 waves/CU (1 block), set by the 256-total-reg bucket.
__global__ __launch_bounds__(512, 2) void fused_mlp(
    const float* __restrict__ feats,
    const f16* __restrict__ w0t, const float* __restrict__ b0,
    const f16* __restrict__ w1t, const float* __restrict__ b1,
    const f16* __restrict__ w2t, const float* __restrict__ b2,
    const f16* __restrict__ wot, const float* __restrict__ bo,
    f16* __restrict__ tree, float* __restrict__ dOut, int lvl, int leaf)
{
  extern __shared__ f16 S[];
  f16* H = S;            // 65536 f16 = 128KB
  f16* X = S;            // layer-0 input (alias of H)

  const int tid  = threadIdx.x;
  const int wave = tid >> 6;
  const int lane = tid & 63;
  const int quad = lane >> 4;
  const int l16  = lane & 15;
  const long rowBase = (long)blockIdx.x * 128;

  // ---- staging: one thread per quarter-row (row math computed ONCE) ----
  {
    const int r = tid >> 2;        // 128 rows x 4 threads
    const int p = tid & 3;
    if (leaf) {
      const float* fsrc = feats + (rowBase + r) * 64 + p * 16;
      f16* xr = X + r * 72 + p * 16;
#pragma unroll
      for (int j = 0; j < 4; j++) {
        float4 v = *(const float4*)(fsrc + j * 4);
        f16x4 h; h[0] = (f16)v.x; h[1] = (f16)v.y; h[2] = (f16)v.z; h[3] = (f16)v.w;
        *(f16x4*)(xr + j * 4) = h;
      }
    } else {
      long rg = rowBase + r;
      long bbr = rg >> lvl;
      long ii = rg - (bbr << lvl);
      long nn = (1L << lvl) - 1 + ii;
      const float* fsrc = feats + (bbr * N_INTN + nn) * 64 + p * 16;
      f16* xr = X + r * 232;
#pragma unroll
      for (int j = 0; j < 4; j++) {
        float4 v = *(const float4*)(fsrc + j * 4);
        f16x4 h; h[0] = (f16)v.x; h[1] = (f16)v.y; h[2] = (f16)v.z; h[3] = (f16)v.w;
        *(f16x4*)(xr + p * 16 + j * 4) = h;
      }
      // children: 66 u32 verbatim (tree col65 junk lands at k=129/195 where
      // weight rows are ZERO via hole-repack; col65 itself zeroed by epilogue)
      const uint32_t* csrc = (const uint32_t*)(tree + (bbr * N_NODE + 2 * nn + 1) * TREE_STRIDE);
      uint32_t* xd = (uint32_t*)(xr + 64);
#pragma unroll
      for (int j = 0; j < 17; j++) {
        int c = p * 17 + j;
        if (c < 66) xd[c] = csrc[c];
      }
#pragma unroll
      for (int j = 0; j < 7; j++) xr[196 + p * 7 + j] = (f16)0.f;  // k=196..223
    }
    __syncthreads();
  }

  // ---- layer 0 (A from X) ----
  if (leaf) {
    auto gA = [&](int c, int mt) -> f16x8 {
      int row = mt * 16 + l16;
      return *(const f16x8*)&X[row * 72 + c * 32 + quad * 8];   // max 63 < 72
    };
    run_layer<64>(w0t, b0, H, wave, lane, quad, l16, gA);
  } else {
    auto gA = [&](int c, int mt) -> f16x8 {
      int row = mt * 16 + l16;
      return *(const f16x8*)&X[row * 232 + c * 32 + quad * 8];  // max 223 < 232
    };
    run_layer<224>(w0t, b0, H, wave, lane, quad, l16, gA);
  }

  // ---- mid layers (A from H) ----
  auto getAH = [&](int c, int mt) -> f16x8 {
    int row = mt * 16 + l16;
    return *(const f16x8*)&H[row * 512 + ((((c * 4 + quad) ^ l16) << 3))];
  };
  run_layer<512>(w1t, b1, H, wave, lane, quad, l16, getAH);
  run_layer<512>(w2t, b2, H, wave, lane, quad, l16, getAH);

  // ---- out layer (512 -> 65), all 8 waves, 16 rows each ----
  {
    const f16* obase = wot + lane * 8;             // frag-linear, NB=5
    auto gB = [&](int c, int nt) -> f16x8 {
      return *(const f16x8*)(obase + (long)(c * 5 + nt) * 512);
    };
    const int orow = wave * 16 + l16;
    auto gA = [&](int c, int mt) -> f16x8 {
      return *(const f16x8*)&H[orow * 512 + ((((c * 4 + quad) ^ l16) << 3))];
    };
    f32x4 oacc[1][5];
#pragma unroll
    for (int i = 0; i < 5; i++) oacc[0][i] = f32x4{0.f, 0.f, 0.f, 0.f};

    kloop<16, 1, 5, false>(gB, gA, oacc);    // normal: row=quad*4+r, col=nt*16+l16

    // hoisted per-row tree pointers
    const long rgb = rowBase + wave * 16 + quad * 4;
    f16* tptr[4];
#pragma unroll
    for (int r = 0; r < 4; r++) {
      long rg = rgb + r;
      long b2_ = rg >> lvl;
      long ii  = rg - (b2_ << lvl);
      long node = (1L << lvl) - 1 + ii;
      tptr[r] = tree + (b2_ * N_NODE + node) * TREE_STRIDE;
    }
#pragma unroll
    for (int nt = 0; nt < 5; nt++)
#pragma unroll
      for (int r = 0; r < 4; r++) {
        int col = nt * 16 + l16;
        if (col < OUT_DIM) {
          float v = oacc[0][nt][r] + bo[col];
          tptr[r][col] = (f16)v;
          if (lvl == 0 && col == 0) dOut[rgb + r] = v;  // lvl 0: row = batch idx
        } else if (col == OUT_DIM) {
          tptr[r][col] = (f16)0.f;   // zero pad col for child verbatim-copies
        }
      }
  }
}

// ---------------- weight repack: transpose+cast to FRAGMENT-LINEAR ----------
// elem e of a segment: j=e&7, lane=(e>>3)&63, q=e>>9, cb=q%NB, c=q/NB;
// stores W[k= c*32+(lane>>4)*8+j][col= cb*16+(lane&15)] (0-padded).
// hole: logical row `hole` is a ZERO row and source rows shift by 1 above it
// (maps the verbatim child-copy junk slots k=129/195 to zero weights).
struct WSeg { const float* W; f16* Wt; int K, N, NB, hole, start; };
struct WPack { WSeg s[8]; int total; };

__global__ void wcast_all(WPack p) {
  int idx = blockIdx.x * 256 + threadIdx.x;
  if (idx >= p.total) return;
  int si = 0;
#pragma unroll
  for (int i = 1; i < 8; i++) if (idx >= p.s[i].start) si = i;
  WSeg sg = p.s[si];
  int e = idx - sg.start;
  int j = e & 7, lane = (e >> 3) & 63, q = e >> 9;
  int cb = q % sg.NB, c = q / sg.NB;
  int col = cb * 16 + (lane & 15);
  int k = c * 32 + (lane >> 4) * 8 + j;
  int srck = (k < sg.hole) ? k : k - 1;
  float v = (k != sg.hole && srck < sg.K && col < sg.N)
                ? sg.W[(long)srck * sg.N + col] : 0.f;
  sg.Wt[e] = (f16)v;
}

// ---------------- host orchestration ----------------
extern "C" void kernel_launch(void* const* d_in, const int* in_sizes, int n_in,
                              void* d_out, int out_size, void* d_ws, size_t ws_size,
                              hipStream_t stream) {
  const float* leaf_feats     = (const float*)d_in[0];
  const float* internal_feats = (const float*)d_in[1];
  const float* lw0 = (const float*)d_in[2];
  const float* lb0 = (const float*)d_in[3];
  const float* lw1 = (const float*)d_in[4];
  const float* lb1 = (const float*)d_in[5];
  const float* lw2 = (const float*)d_in[6];
  const float* lb2 = (const float*)d_in[7];
  const float* lwo = (const float*)d_in[8];
  const float* lbo = (const float*)d_in[9];
  const float* iw0 = (const float*)d_in[10];
  const float* ib0 = (const float*)d_in[11];
  const float* iw1 = (const float*)d_in[12];
  const float* ib1 = (const float*)d_in[13];
  const float* iw2 = (const float*)d_in[14];
  const float* ib2 = (const float*)d_in[15];
  const float* iwo = (const float*)d_in[16];
  const float* ibo = (const float*)d_in[17];
  float* dOut = (float*)d_out;

  char* ws = (char*)d_ws;
  size_t off = 0;
  auto alloc = [&](size_t bytes) -> void* {
    void* p = ws + off;
    off += (bytes + 255) & ~(size_t)255;
    return p;
  };

  f16* lw0t = (f16*)alloc((size_t)64  * 512 * 2);
  f16* lw1t = (f16*)alloc((size_t)512 * 512 * 2);
  f16* lw2t = (f16*)alloc((size_t)512 * 512 * 2);
  f16* lwot = (f16*)alloc((size_t)512 * 80  * 2);
  f16* iw0t = (f16*)alloc((size_t)224 * 512 * 2);
  f16* iw1t = (f16*)alloc((size_t)512 * 512 * 2);
  f16* iw2t = (f16*)alloc((size_t)512 * 512 * 2);
  f16* iwot = (f16*)alloc((size_t)512 * 80  * 2);
  f16* tree = (f16*)alloc((size_t)256 * N_NODE * TREE_STRIDE * 2);

  const int NOHOLE = 1 << 30;
  WPack p;
  int cum = 0;
  auto seg = [&](int i, const float* W, f16* Wt, int K, int N, int Kpad, int NB, int hole) {
    p.s[i] = {W, Wt, K, N, NB, hole, cum};
    cum += Kpad * NB * 16;
  };
  seg(0, lw0, lw0t, 64, 512, 64, 32, NOHOLE);
  seg(1, lw1, lw1t, 512, 512, 512, 32, NOHOLE);
  seg(2, lw2, lw2t, 512, 512, 512, 32, NOHOLE);
  seg(3, lwo, lwot, 512, 65, 512, 5, NOHOLE);
  seg(4, iw0, iw0t, 194, 512, 224, 32, 129);   // hole at k=129 (left child pad)
  seg(5, iw1, iw1t, 512, 512, 512, 32, NOHOLE);
  seg(6, iw2, iw2t, 512, 512, 512, 32, NOHOLE);
  seg(7, iwo, iwot, 512, 65, 512, 5, NOHOLE);
  p.total = cum;
  wcast_all<<<dim3((cum + 255) / 256), dim3(256), 0, stream>>>(p);

  static bool attrSet = false;
  if (!attrSet) {
    hipFuncSetAttribute(reinterpret_cast<const void*>(fused_mlp),
                        hipFuncAttributeMaxDynamicSharedMemorySize, 131072);
    attrSet = true;
  }

  const size_t shmem = 131072;   // H 128KB (X aliased)

  // leaf pass: 131072 rows -> nodes 511..1022
  fused_mlp<<<dim3(1024), dim3(512), shmem, stream>>>(
      leaf_feats, lw0t, lb0, lw1t, lb1, lw2t, lb2, lwot, lbo, tree, dOut, 9, 1);

  // internal levels 8..0 (grid = rows/128 = 2<<l; weights stay L2-hot)
  for (int l = 8; l >= 0; l--) {
    fused_mlp<<<dim3(2u << l), dim3(512), shmem, stream>>>(
        internal_feats, iw0t, ib0, iw1t, ib1, iw2t, ib2, iwot, ibo, tree, dOut, l, 0);
  }

  (void)in_sizes; (void)n_in; (void)out_size; (void)ws_size;
}

// Round 11
// 708.620 us; speedup vs baseline: 1.4145x; 1.1856x over previous
//
#include <hip/hip_runtime.h>
#include <cstdint>
#include <cstddef>
#include <type_traits>

// ---------------- problem constants ----------------
#define OUT_DIM    65
#define TREE_STRIDE 66
#define N_NODE     1023
#define N_INTN     511

typedef _Float16 f16;
typedef _Float16 f16x8 __attribute__((ext_vector_type(8)));
typedef _Float16 f16x4 __attribute__((ext_vector_type(4)));
typedef float    f32x4 __attribute__((ext_vector_type(4)));

template<int V> using ic = std::integral_constant<int, V>;

#define MFMA(a, b, c) __builtin_amdgcn_mfma_f32_16x16x32_f16((a), (b), (c), 0, 0, 0)

// counted wait, compile-time immediates; "memory" clobber pins load scheduling.
// Correctness never relies on these (compiler emits its own waits before each
// use of a loaded value); they only ADD earlier/looser waits for scheduling.
template<int VM, int LG>
__device__ __forceinline__ void waitcnt_t() {
  asm volatile("s_waitcnt vmcnt(%0) lgkmcnt(%1)" :: "n"(VM), "n"(LG) : "memory");
}

// H swizzle: elem(row,k) at row*512 + (((k>>3) ^ (row&15))<<3) + (k&7)
template<int MT>
__device__ __forceinline__ void storeH_fn(f16* __restrict__ H, f32x4 (&acc)[MT][4],
                                          const float* __restrict__ bias,
                                          int wcb, int quad, int l16) {
#pragma unroll
  for (int mt = 0; mt < MT; mt++) {
#pragma unroll
    for (int nt = 0; nt < 4; nt++) {
      const int c0 = wcb + nt * 16 + quad * 4;
      const float4 bv = *(const float4*)(bias + c0);
      f16x4 hv;
      float v0 = acc[mt][nt][0] + bv.x; hv[0] = (f16)(v0 > 0.f ? v0 : 0.f);
      float v1 = acc[mt][nt][1] + bv.y; hv[1] = (f16)(v1 > 0.f ? v1 : 0.f);
      float v2 = acc[mt][nt][2] + bv.z; hv[2] = (f16)(v2 > 0.f ? v2 : 0.f);
      float v3 = acc[mt][nt][3] + bv.w; hv[3] = (f16)(v3 > 0.f ? v3 : 0.f);
      const int row = mt * 16 + l16;
      *(f16x4*)&H[row * 512 + (((c0 >> 3) ^ l16) << 3) + (quad & 1) * 4] = hv;
    }
  }
}

// ---------------------------------------------------------------------------
// Barrier-free K-loop. B: global->VGPR from FRAGMENT-LINEAR weights (one
// coalesced 1KB dwordx4 per load). A: ds_read from stable LDS. BD/AD rings
// with counted waits; no __syncthreads inside — waves drift freely.
// REGISTER REGIME (the session's binding constraint): per-SIMD pool = 512
// regs (wave64); occupancy buckets at 64/128/256 total(arch+acc) per wave.
//   MT=4 (64-row tile): acc 64 -> ~184 total -> 2 waves/SIMD (rounds 6/8).
//   MT=2 (32-row tile): acc 32 -> ~105 total -> 4 waves/SIMD, 2 blocks/CU.
//   MT=8: acc 128 -> arch capped at 128 -> ALWAYS spills (rounds 4/5/9/10).
// ---------------------------------------------------------------------------
template<int NC, int MT, int NT, int BD, int AD, bool SWAP,
         typename GetB, typename GetA>
__device__ __forceinline__ void kloop(GetB getB, GetA getA, f32x4 (&acc)[MT][NT])
{
  f16x8 bs[BD][NT];
  f16x8 as[AD][MT];
#pragma unroll
  for (int c = 0; c < BD - 1 && c < NC; c++)
#pragma unroll
    for (int nt = 0; nt < NT; nt++) bs[c][nt] = getB(c, nt);
#pragma unroll
  for (int c = 0; c < AD - 1 && c < NC; c++)
#pragma unroll
    for (int mt = 0; mt < MT; mt++) as[c][mt] = getA(c, mt);

  auto lp = [&](auto&& self, auto Cc) -> void {
    constexpr int C = decltype(Cc)::value;
    if constexpr (C < NC) {
      if constexpr (C + BD - 1 < NC) {
#pragma unroll
        for (int nt = 0; nt < NT; nt++) bs[(C + BD - 1) % BD][nt] = getB(C + BD - 1, nt);
      }
      if constexpr (C + AD - 1 < NC) {
#pragma unroll
        for (int mt = 0; mt < MT; mt++) as[(C + AD - 1) % AD][mt] = getA(C + AD - 1, mt);
      }
      constexpr int BOUT = (BD - 1) < (NC - 1 - C) ? (BD - 1) : (NC - 1 - C);
      constexpr int AOUT = (AD - 1) < (NC - 1 - C) ? (AD - 1) : (NC - 1 - C);
      waitcnt_t<NT * BOUT, MT * AOUT>();
      __builtin_amdgcn_s_setprio(1);
#pragma unroll
      for (int mt = 0; mt < MT; mt++)
#pragma unroll
        for (int nt = 0; nt < NT; nt++)
          acc[mt][nt] = SWAP ? MFMA(bs[C % BD][nt], as[C % AD][mt], acc[mt][nt])
                             : MFMA(as[C % AD][mt], bs[C % BD][nt], acc[mt][nt]);
      __builtin_amdgcn_s_setprio(0);
      self(self, ic<C + 1>{});
    }
  };
  lp(lp, ic<0>{});
}

// one 512-col layer, 32 rows (MT=2), 8 waves each owning 64 cols.
// B fragment-linear: frag(c, cb, lane) at ((c*32 + cb)*64 + lane)*8 f16,
// cb = wave*4 + nt (layout unchanged from rounds 6-10).
template<int K, typename GetA>
__device__ __forceinline__ void run_layer(
    const f16* __restrict__ Wt, const float* __restrict__ bias,
    f16* __restrict__ H, int wave, int lane, int quad, int l16, GetA getA)
{
  constexpr int NC = K / 32;
  const int wcb = wave * 64;
  const f16* bbase = Wt + (long)(wave * 4) * 512 + lane * 8;
  auto getB = [&](int c, int nt) -> f16x8 {
    return *(const f16x8*)(bbase + (long)(c * 32 + nt) * 512);
  };
  f32x4 acc[2][4];
#pragma unroll
  for (int i = 0; i < 2; i++)
#pragma unroll
    for (int j = 0; j < 4; j++) acc[i][j] = f32x4{0.f, 0.f, 0.f, 0.f};

  kloop<NC, 2, 4, 2, 2, true>(getB, getA, acc);   // swapped: row=l16, col=quad*4+r

  __syncthreads();                 // all H/X reads of this layer done
  storeH_fn<2>(H, acc, bias, wcb, quad, l16);
  __syncthreads();                 // H visible for next layer
}

// ---------------- fused 4-layer MLP, 32 rows/block, 512 thr, any level ------
// LDS: H[32][512] f16 = 32KB -> 2 blocks/CU (reg-bucket-limited: ~105 total
// regs/wave fits the 128 bucket -> 4 waves/SIMD). __launch_bounds__(512,4)
// caps total(arch+acc) at 128 — SAFE here because demand ~105 (round 7's
// disaster was the same cap with demand ~190).
// X (layer-0 input) aliases H — safe: storeH(l0) writes H only after the
// barrier when all X reads are done. leaf X[32][72], internal X[32][232].
__global__ __launch_bounds__(512, 4) void fused_mlp(
    const float* __restrict__ feats,
    const f16* __restrict__ w0t, const float* __restrict__ b0,
    const f16* __restrict__ w1t, const float* __restrict__ b1,
    const f16* __restrict__ w2t, const float* __restrict__ b2,
    const f16* __restrict__ wot, const float* __restrict__ bo,
    f16* __restrict__ tree, float* __restrict__ dOut, int lvl, int leaf)
{
  extern __shared__ f16 S[];
  f16* H = S;            // 16384 f16 = 32KB
  f16* X = S;            // layer-0 input (alias of H)

  const int tid  = threadIdx.x;
  const int wave = tid >> 6;
  const int lane = tid & 63;
  const int quad = lane >> 4;
  const int l16  = lane & 15;
  const long rowBase = (long)blockIdx.x * 32;

  // ---- staging: 16 threads per row (row math computed ONCE per thread) ----
  {
    const int r = tid >> 4;        // 32 rows x 16 threads
    const int p = tid & 15;
    if (leaf) {
      const float* fsrc = feats + (rowBase + r) * 64 + p * 4;
      float4 v = *(const float4*)fsrc;
      f16x4 h; h[0] = (f16)v.x; h[1] = (f16)v.y; h[2] = (f16)v.z; h[3] = (f16)v.w;
      *(f16x4*)(X + r * 72 + p * 4) = h;
    } else {
      long rg = rowBase + r;
      long bbr = rg >> lvl;
      long ii = rg - (bbr << lvl);
      long nn = (1L << lvl) - 1 + ii;
      const float* fsrc = feats + (bbr * N_INTN + nn) * 64 + p * 4;
      f16* xr = X + r * 232;
      float4 v = *(const float4*)fsrc;
      f16x4 h; h[0] = (f16)v.x; h[1] = (f16)v.y; h[2] = (f16)v.z; h[3] = (f16)v.w;
      *(f16x4*)(xr + p * 4) = h;
      // children: 66 u32 verbatim (tree col65 junk lands at k=129/195 where
      // weight rows are ZERO via hole-repack; col65 itself zeroed by epilogue)
      const uint32_t* csrc = (const uint32_t*)(tree + (bbr * N_NODE + 2 * nn + 1) * TREE_STRIDE);
      uint32_t* xd = (uint32_t*)(xr + 64);
#pragma unroll
      for (int j = 0; j < 5; j++) {
        int c = p * 5 + j;
        if (c < 66) xd[c] = csrc[c];
      }
#pragma unroll
      for (int j = 0; j < 2; j++) {            // zero k=196..223
        int z = p * 2 + j;
        if (z < 28) xr[196 + z] = (f16)0.f;
      }
    }
    __syncthreads();
  }

  // ---- layer 0 (A from X) ----
  if (leaf) {
    auto gA = [&](int c, int mt) -> f16x8 {
      int row = mt * 16 + l16;
      return *(const f16x8*)&X[row * 72 + c * 32 + quad * 8];   // max 63 < 72
    };
    run_layer<64>(w0t, b0, H, wave, lane, quad, l16, gA);
  } else {
    auto gA = [&](int c, int mt) -> f16x8 {
      int row = mt * 16 + l16;
      return *(const f16x8*)&X[row * 232 + c * 32 + quad * 8];  // max 223 < 232
    };
    run_layer<224>(w0t, b0, H, wave, lane, quad, l16, gA);
  }

  // ---- mid layers (A from H) ----
  auto getAH = [&](int c, int mt) -> f16x8 {
    int row = mt * 16 + l16;
    return *(const f16x8*)&H[row * 512 + ((((c * 4 + quad) ^ l16) << 3))];
  };
  run_layer<512>(w1t, b1, H, wave, lane, quad, l16, getAH);
  run_layer<512>(w2t, b2, H, wave, lane, quad, l16, getAH);

  // ---- out layer (512 -> 65, padded 128 cols), ALL 8 waves:
  //      wave w: row-group g=w&1 (16 rows), col-pair cp=w>>1 (2x16 cols) ----
  {
    const int g  = wave & 1;
    const int cp = wave >> 1;
    const f16* obase = wot + (long)(cp * 2) * 512 + lane * 8;   // frag-linear NB=8
    auto gB = [&](int c, int nt) -> f16x8 {
      return *(const f16x8*)(obase + (long)(c * 8 + nt) * 512);
    };
    const int orow = g * 16 + l16;
    auto gA = [&](int c, int mt) -> f16x8 {
      return *(const f16x8*)&H[orow * 512 + ((((c * 4 + quad) ^ l16) << 3))];
    };
    f32x4 oacc[1][2];
    oacc[0][0] = f32x4{0.f, 0.f, 0.f, 0.f};
    oacc[0][1] = f32x4{0.f, 0.f, 0.f, 0.f};

    kloop<16, 1, 2, 2, 2, false>(gB, gA, oacc);  // normal: row=quad*4+r, col=cp*32+nt*16+l16

    const long rgb = rowBase + g * 16 + quad * 4;
    f16* tptr[4];
#pragma unroll
    for (int r = 0; r < 4; r++) {
      long rg = rgb + r;
      long b2_ = rg >> lvl;
      long ii  = rg - (b2_ << lvl);
      long node = (1L << lvl) - 1 + ii;
      tptr[r] = tree + (b2_ * N_NODE + node) * TREE_STRIDE;
    }
#pragma unroll
    for (int nt = 0; nt < 2; nt++)
#pragma unroll
      for (int r = 0; r < 4; r++) {
        int col = cp * 32 + nt * 16 + l16;
        if (col < OUT_DIM) {
          float v = oacc[0][nt][r] + bo[col];
          tptr[r][col] = (f16)v;
          if (lvl == 0 && col == 0) dOut[rgb + r] = v;  // lvl 0: row = batch idx
        } else if (col == OUT_DIM) {
          tptr[r][col] = (f16)0.f;   // zero pad col for child verbatim-copies
        }
      }
  }
}

// ---------------- weight repack: transpose+cast to FRAGMENT-LINEAR ----------
// elem e of a segment: j=e&7, lane=(e>>3)&63, q=e>>9, cb=q%NB, c=q/NB;
// stores W[k= c*32+(lane>>4)*8+j][col= cb*16+(lane&15)] (0-padded).
// hole: logical row `hole` is a ZERO row and source rows shift by 1 above it
// (maps the verbatim child-copy junk slots k=129/195 to zero weights).
struct WSeg { const float* W; f16* Wt; int K, N, NB, hole, start; };
struct WPack { WSeg s[8]; int total; };

__global__ void wcast_all(WPack p) {
  int idx = blockIdx.x * 256 + threadIdx.x;
  if (idx >= p.total) return;
  int si = 0;
#pragma unroll
  for (int i = 1; i < 8; i++) if (idx >= p.s[i].start) si = i;
  WSeg sg = p.s[si];
  int e = idx - sg.start;
  int j = e & 7, lane = (e >> 3) & 63, q = e >> 9;
  int cb = q % sg.NB, c = q / sg.NB;
  int col = cb * 16 + (lane & 15);
  int k = c * 32 + (lane >> 4) * 8 + j;
  int srck = (k < sg.hole) ? k : k - 1;
  float v = (k != sg.hole && srck < sg.K && col < sg.N)
                ? sg.W[(long)srck * sg.N + col] : 0.f;
  sg.Wt[e] = (f16)v;
}

// ---------------- host orchestration ----------------
extern "C" void kernel_launch(void* const* d_in, const int* in_sizes, int n_in,
                              void* d_out, int out_size, void* d_ws, size_t ws_size,
                              hipStream_t stream) {
  const float* leaf_feats     = (const float*)d_in[0];
  const float* internal_feats = (const float*)d_in[1];
  const float* lw0 = (const float*)d_in[2];
  const float* lb0 = (const float*)d_in[3];
  const float* lw1 = (const float*)d_in[4];
  const float* lb1 = (const float*)d_in[5];
  const float* lw2 = (const float*)d_in[6];
  const float* lb2 = (const float*)d_in[7];
  const float* lwo = (const float*)d_in[8];
  const float* lbo = (const float*)d_in[9];
  const float* iw0 = (const float*)d_in[10];
  const float* ib0 = (const float*)d_in[11];
  const float* iw1 = (const float*)d_in[12];
  const float* ib1 = (const float*)d_in[13];
  const float* iw2 = (const float*)d_in[14];
  const float* ib2 = (const float*)d_in[15];
  const float* iwo = (const float*)d_in[16];
  const float* ibo = (const float*)d_in[17];
  float* dOut = (float*)d_out;

  char* ws = (char*)d_ws;
  size_t off = 0;
  auto alloc = [&](size_t bytes) -> void* {
    void* p = ws + off;
    off += (bytes + 255) & ~(size_t)255;
    return p;
  };

  f16* lw0t = (f16*)alloc((size_t)64  * 512 * 2);
  f16* lw1t = (f16*)alloc((size_t)512 * 512 * 2);
  f16* lw2t = (f16*)alloc((size_t)512 * 512 * 2);
  f16* lwot = (f16*)alloc((size_t)512 * 128 * 2);
  f16* iw0t = (f16*)alloc((size_t)224 * 512 * 2);
  f16* iw1t = (f16*)alloc((size_t)512 * 512 * 2);
  f16* iw2t = (f16*)alloc((size_t)512 * 512 * 2);
  f16* iwot = (f16*)alloc((size_t)512 * 128 * 2);
  f16* tree = (f16*)alloc((size_t)256 * N_NODE * TREE_STRIDE * 2);

  const int NOHOLE = 1 << 30;
  WPack p;
  int cum = 0;
  auto seg = [&](int i, const float* W, f16* Wt, int K, int N, int Kpad, int NB, int hole) {
    p.s[i] = {W, Wt, K, N, NB, hole, cum};
    cum += Kpad * NB * 16;
  };
  seg(0, lw0, lw0t, 64, 512, 64, 32, NOHOLE);
  seg(1, lw1, lw1t, 512, 512, 512, 32, NOHOLE);
  seg(2, lw2, lw2t, 512, 512, 512, 32, NOHOLE);
  seg(3, lwo, lwot, 512, 65, 512, 8, NOHOLE);
  seg(4, iw0, iw0t, 194, 512, 224, 32, 129);   // hole at k=129 (left child pad)
  seg(5, iw1, iw1t, 512, 512, 512, 32, NOHOLE);
  seg(6, iw2, iw2t, 512, 512, 512, 32, NOHOLE);
  seg(7, iwo, iwot, 512, 65, 512, 8, NOHOLE);
  p.total = cum;
  wcast_all<<<dim3((cum + 255) / 256), dim3(256), 0, stream>>>(p);

  static bool attrSet = false;
  if (!attrSet) {
    hipFuncSetAttribute(reinterpret_cast<const void*>(fused_mlp),
                        hipFuncAttributeMaxDynamicSharedMemorySize, 32768);
    attrSet = true;
  }

  const size_t shmem = 32768;   // H 32KB (X aliased) -> 2 blocks/CU

  // leaf pass: 131072 rows -> nodes 511..1022
  fused_mlp<<<dim3(4096), dim3(512), shmem, stream>>>(
      leaf_feats, lw0t, lb0, lw1t, lb1, lw2t, lb2, lwot, lbo, tree, dOut, 9, 1);

  // internal levels 8..0 (grid = rows/32 = 8<<l; weights stay L2-hot)
  for (int l = 8; l >= 0; l--) {
    fused_mlp<<<dim3(8u << l), dim3(512), shmem, stream>>>(
        internal_feats, iw0t, ib0, iw1t, ib1, iw2t, ib2, iwot, ibo, tree, dOut, l, 0);
  }

  (void)in_sizes; (void)n_in; (void)out_size; (void)ws_size;
}